// Round 8
// baseline (352.707 us; speedup 1.0000x reference)
//
#include <hip/hip_runtime.h>
#include <stdint.h>

#define TOL 1e-2f
#define WPB 4
// ws layout: [0..128): 8 hashed flag slots (2 u64 each); [192..200): ctl {S, ok};
// [4096 ..): z checkpoints, one 2 MB slab per step k (slot k-1).
#define WS_CTL_OFF 192
#define WS_Z_OFF   4096

__device__ __forceinline__ float bcastf(float v, int l) {
    return __int_as_float(__builtin_amdgcn_readlane(__float_as_int(v), l));
}
template <int PAT>
__device__ __forceinline__ float swz(float v) {
    return __int_as_float(__builtin_amdgcn_ds_swizzle(__float_as_int(v), PAT));
}
#define SWZ_XOR16 0x401F   // src = lane ^ 16

// The entire 48-MAC broadcast-matvec as ONE asm block: W pinned to arch VGPRs,
// readlane->SGPR software-pipelined (depth 3) to satisfy the 2-wait-state
// VALU-writes-SGPR -> VALU-reads-SGPR hazard. s_nop 1 covers the preceding
// VALU write of vs before the first readlane.
#define MACS(a0,a1,a2,a3,vs,vh,Wp) \
  asm("s_nop 1\n\t" \
      "v_readlane_b32 s20, %[vs], 0\n\t" \
      "v_readlane_b32 s21, %[vs], 1\n\t" \
      "v_readlane_b32 s22, %[vs], 2\n\t" \
      "v_fmac_f32 %[a0], s20, %[w0]\n\t"  "v_readlane_b32 s20, %[vs], 3\n\t" \
      "v_fmac_f32 %[a1], s21, %[w1]\n\t"  "v_readlane_b32 s21, %[vs], 4\n\t" \
      "v_fmac_f32 %[a2], s22, %[w2]\n\t"  "v_readlane_b32 s22, %[vs], 5\n\t" \
      "v_fmac_f32 %[a3], s20, %[w3]\n\t"  "v_readlane_b32 s20, %[vs], 6\n\t" \
      "v_fmac_f32 %[a0], s21, %[w4]\n\t"  "v_readlane_b32 s21, %[vs], 7\n\t" \
      "v_fmac_f32 %[a1], s22, %[w5]\n\t"  "v_readlane_b32 s22, %[vs], 8\n\t" \
      "v_fmac_f32 %[a2], s20, %[w6]\n\t"  "v_readlane_b32 s20, %[vs], 9\n\t" \
      "v_fmac_f32 %[a3], s21, %[w7]\n\t"  "v_readlane_b32 s21, %[vs], 10\n\t" \
      "v_fmac_f32 %[a0], s22, %[w8]\n\t"  "v_readlane_b32 s22, %[vs], 11\n\t" \
      "v_fmac_f32 %[a1], s20, %[w9]\n\t"  "v_readlane_b32 s20, %[vs], 12\n\t" \
      "v_fmac_f32 %[a2], s21, %[w10]\n\t" "v_readlane_b32 s21, %[vs], 13\n\t" \
      "v_fmac_f32 %[a3], s22, %[w11]\n\t" "v_readlane_b32 s22, %[vs], 14\n\t" \
      "v_fmac_f32 %[a0], s20, %[w12]\n\t" "v_readlane_b32 s20, %[vs], 15\n\t" \
      "v_fmac_f32 %[a1], s21, %[w13]\n\t" "v_readlane_b32 s21, %[vh], 32\n\t" \
      "v_fmac_f32 %[a2], s22, %[w14]\n\t" "v_readlane_b32 s22, %[vh], 33\n\t" \
      "v_fmac_f32 %[a3], s20, %[w15]\n\t" "v_readlane_b32 s20, %[vh], 34\n\t" \
      "v_fmac_f32 %[a0], s21, %[w16]\n\t" "v_readlane_b32 s21, %[vh], 35\n\t" \
      "v_fmac_f32 %[a1], s22, %[w17]\n\t" "v_readlane_b32 s22, %[vh], 36\n\t" \
      "v_fmac_f32 %[a2], s20, %[w18]\n\t" "v_readlane_b32 s20, %[vh], 37\n\t" \
      "v_fmac_f32 %[a3], s21, %[w19]\n\t" "v_readlane_b32 s21, %[vh], 38\n\t" \
      "v_fmac_f32 %[a0], s22, %[w20]\n\t" "v_readlane_b32 s22, %[vh], 39\n\t" \
      "v_fmac_f32 %[a1], s20, %[w21]\n\t" "v_readlane_b32 s20, %[vh], 40\n\t" \
      "v_fmac_f32 %[a2], s21, %[w22]\n\t" "v_readlane_b32 s21, %[vh], 41\n\t" \
      "v_fmac_f32 %[a3], s22, %[w23]\n\t" "v_readlane_b32 s22, %[vh], 42\n\t" \
      "v_fmac_f32 %[a0], s20, %[w24]\n\t" "v_readlane_b32 s20, %[vh], 43\n\t" \
      "v_fmac_f32 %[a1], s21, %[w25]\n\t" "v_readlane_b32 s21, %[vh], 44\n\t" \
      "v_fmac_f32 %[a2], s22, %[w26]\n\t" "v_readlane_b32 s22, %[vh], 45\n\t" \
      "v_fmac_f32 %[a3], s20, %[w27]\n\t" "v_readlane_b32 s20, %[vh], 46\n\t" \
      "v_fmac_f32 %[a0], s21, %[w28]\n\t" "v_readlane_b32 s21, %[vh], 47\n\t" \
      "v_fmac_f32 %[a1], s22, %[w29]\n\t" "v_readlane_b32 s22, %[vh], 48\n\t" \
      "v_fmac_f32 %[a2], s20, %[w30]\n\t" "v_readlane_b32 s20, %[vh], 49\n\t" \
      "v_fmac_f32 %[a3], s21, %[w31]\n\t" "v_readlane_b32 s21, %[vh], 50\n\t" \
      "v_fmac_f32 %[a0], s22, %[w32]\n\t" "v_readlane_b32 s22, %[vh], 51\n\t" \
      "v_fmac_f32 %[a1], s20, %[w33]\n\t" "v_readlane_b32 s20, %[vh], 52\n\t" \
      "v_fmac_f32 %[a2], s21, %[w34]\n\t" "v_readlane_b32 s21, %[vh], 53\n\t" \
      "v_fmac_f32 %[a3], s22, %[w35]\n\t" "v_readlane_b32 s22, %[vh], 54\n\t" \
      "v_fmac_f32 %[a0], s20, %[w36]\n\t" "v_readlane_b32 s20, %[vh], 55\n\t" \
      "v_fmac_f32 %[a1], s21, %[w37]\n\t" "v_readlane_b32 s21, %[vh], 56\n\t" \
      "v_fmac_f32 %[a2], s22, %[w38]\n\t" "v_readlane_b32 s22, %[vh], 57\n\t" \
      "v_fmac_f32 %[a3], s20, %[w39]\n\t" "v_readlane_b32 s20, %[vh], 58\n\t" \
      "v_fmac_f32 %[a0], s21, %[w40]\n\t" "v_readlane_b32 s21, %[vh], 59\n\t" \
      "v_fmac_f32 %[a1], s22, %[w41]\n\t" "v_readlane_b32 s22, %[vh], 60\n\t" \
      "v_fmac_f32 %[a2], s20, %[w42]\n\t" "v_readlane_b32 s20, %[vh], 61\n\t" \
      "v_fmac_f32 %[a3], s21, %[w43]\n\t" "v_readlane_b32 s21, %[vh], 62\n\t" \
      "v_fmac_f32 %[a0], s22, %[w44]\n\t" "v_readlane_b32 s22, %[vh], 63\n\t" \
      "v_fmac_f32 %[a1], s20, %[w45]\n\t" \
      "v_fmac_f32 %[a2], s21, %[w46]\n\t" \
      "v_fmac_f32 %[a3], s22, %[w47]\n\t" \
      : [a0]"+v"(a0), [a1]"+v"(a1), [a2]"+v"(a2), [a3]"+v"(a3) \
      : [vs]"v"(vs), [vh]"v"(vh), \
        [w0]"v"(Wp[0]),  [w1]"v"(Wp[1]),  [w2]"v"(Wp[2]),  [w3]"v"(Wp[3]), \
        [w4]"v"(Wp[4]),  [w5]"v"(Wp[5]),  [w6]"v"(Wp[6]),  [w7]"v"(Wp[7]), \
        [w8]"v"(Wp[8]),  [w9]"v"(Wp[9]),  [w10]"v"(Wp[10]),[w11]"v"(Wp[11]), \
        [w12]"v"(Wp[12]),[w13]"v"(Wp[13]),[w14]"v"(Wp[14]),[w15]"v"(Wp[15]), \
        [w16]"v"(Wp[16]),[w17]"v"(Wp[17]),[w18]"v"(Wp[18]),[w19]"v"(Wp[19]), \
        [w20]"v"(Wp[20]),[w21]"v"(Wp[21]),[w22]"v"(Wp[22]),[w23]"v"(Wp[23]), \
        [w24]"v"(Wp[24]),[w25]"v"(Wp[25]),[w26]"v"(Wp[26]),[w27]"v"(Wp[27]), \
        [w28]"v"(Wp[28]),[w29]"v"(Wp[29]),[w30]"v"(Wp[30]),[w31]"v"(Wp[31]), \
        [w32]"v"(Wp[32]),[w33]"v"(Wp[33]),[w34]"v"(Wp[34]),[w35]"v"(Wp[35]), \
        [w36]"v"(Wp[36]),[w37]"v"(Wp[37]),[w38]"v"(Wp[38]),[w39]"v"(Wp[39]), \
        [w40]"v"(Wp[40]),[w41]"v"(Wp[41]),[w42]"v"(Wp[42]),[w43]"v"(Wp[43]), \
        [w44]"v"(Wp[44]),[w45]"v"(Wp[45]),[w46]"v"(Wp[46]),[w47]"v"(Wp[47]) \
      : "s20", "s21", "s22")

// MODE 0: run mi steps from z0; checkpoint every step; record per-step residual bits.
// MODE 1: fallback replay (only if ctl[1]==0): run ctl[0] steps, write out.
template <int MODE>
__global__ __launch_bounds__(256) void dys_pass(
    const float* __restrict__ u_nom,     // (B,16)
    const float* __restrict__ Amat,      // (B,32,16)
    const float* __restrict__ bvec,      // (B,32)
    const int*   __restrict__ mi_ptr,
    const int*   __restrict__ ctl,       // {S, stored_ok}
    unsigned long long* __restrict__ flags,
    float*       __restrict__ zstore,
    int zcap,
    float*       __restrict__ out,
    int B)
{
    if (MODE == 1) { if (ctl[1]) return; }   // checkpoint path valid: gather handles out

    const int tid   = threadIdx.x;
    const int lane  = tid & 63;
    const int wib   = tid >> 6;
    const int elem  = blockIdx.x * WPB + wib;
    const int row32 = lane & 31;
    const int col16 = lane & 15;

    // Wave-private LDS scratch; same-wave ordering via lgkmcnt, no __syncthreads.
    __shared__ __align__(16) float ldsT[WPB][32 * 17];
    float* T = ldsT[wib];

    // ---- load A row (dup on upper half), u, b ----
    const float* Ab = Amat + (size_t)elem * 512 + (size_t)row32 * 16;
    float A_row[16];
    {
        float4 a0 = ((const float4*)Ab)[0];
        float4 a1 = ((const float4*)Ab)[1];
        float4 a2 = ((const float4*)Ab)[2];
        float4 a3 = ((const float4*)Ab)[3];
        A_row[0]=a0.x;  A_row[1]=a0.y;  A_row[2]=a0.z;  A_row[3]=a0.w;
        A_row[4]=a1.x;  A_row[5]=a1.y;  A_row[6]=a1.z;  A_row[7]=a1.w;
        A_row[8]=a2.x;  A_row[9]=a2.y;  A_row[10]=a2.z; A_row[11]=a2.w;
        A_row[12]=a3.x; A_row[13]=a3.y; A_row[14]=a3.z; A_row[15]=a3.w;
    }
    if (lane < 32) {
        #pragma unroll
        for (int k = 0; k < 16; ++k) T[row32 * 17 + k] = A_row[k];
    }
    const float un = u_nom[(size_t)elem * 16 + col16];
    const float bv = bvec[(size_t)elem * 32 + row32];

    // W layout per lane (after setup):
    //   lanes 0-31  (i = lane&15): [AtQA_i(16) | AtQ_i(32)]
    //   lanes 32-63 (j = lane-32): [QA_j(16)   | Q_j(32)  ]
    float W[48];

    // ---- N = 2*A*A^T + I: row (lane&31) into W[16..47] ----
    {
        float A2[16];
        #pragma unroll
        for (int k = 0; k < 16; ++k) A2[k] = A_row[k] + A_row[k];
        #pragma unroll
        for (int j = 0; j < 32; ++j) {
            float acc = (row32 == j) ? 1.f : 0.f;
            #pragma unroll
            for (int k = 0; k < 16; ++k)
                acc = fmaf(A2[k], bcastf(A_row[k], j), acc);
            W[16 + j] = acc;
        }
    }

    // ---- in-place Gauss-Jordan: W[16..47] -> Q = N^-1 row (lane&31) ----
    #pragma unroll
    for (int p = 0; p < 32; ++p) {
        float piv = bcastf(W[16 + p], p);
        float d = __builtin_amdgcn_rcpf(piv);
        d = d * (2.f - piv * d);                // one Newton step
        float g = W[16 + p] * d;
        g = (row32 == p) ? (1.f - d) : g;
        float negg = -g;
        #pragma unroll
        for (int j = 0; j < 32; ++j) {
            if (j == p) continue;
            float spj = bcastf(W[16 + j], p);   // OLD pivot-row value
            W[16 + j] = fmaf(negg, spj, W[16 + j]);
        }
        W[16 + p] = (row32 == p) ? d : negg;
    }

    // ---- QA row (lane&31) into W[0..15] ----
    #pragma unroll
    for (int k = 0; k < 16; ++k) W[k] = 0.f;
    #pragma unroll
    for (int m = 0; m < 32; ++m) {
        float q = W[16 + m];
        #pragma unroll
        for (int k = 0; k < 16; ++k)
            W[k] = fmaf(q, bcastf(A_row[k], m), W[k]);
    }

    // ---- lanes 0-31: AtQA row i (A staged in T, QA row broadcasts) ----
    float tq[16];
    #pragma unroll
    for (int k = 0; k < 16; ++k) tq[k] = 0.f;
    #pragma unroll
    for (int m = 0; m < 32; ++m) {
        float a_mi = T[m * 17 + col16];          // A[m][i]
        #pragma unroll
        for (int k = 0; k < 16; ++k)
            tq[k] = fmaf(a_mi, bcastf(W[k], m), tq[k]);   // * QA[m][k]
    }

    if (lane < 32) {
        #pragma unroll
        for (int k = 0; k < 16; ++k) T[row32 * 17 + k] = W[k];   // stage QA rows
    }
    if (lane < 32) {
        #pragma unroll
        for (int m = 0; m < 32; ++m) W[16 + m] = T[m * 17 + col16];  // AtQ[i][m]
        #pragma unroll
        for (int k = 0; k < 16; ++k) W[k] = tq[k];                   // AtQA row i
    }

    // ---- fold c = (lanes<32 ? AtQ.b : Q.b) ----
    float cneg;
    {
        float c0 = 0.f, c1 = 0.f;
        #pragma unroll
        for (int m = 0; m < 32; m += 2) {
            c0 = fmaf(W[16 + m], bcastf(bv, m),     c0);
            c1 = fmaf(W[17 + m], bcastf(bv, m + 1), c1);
        }
        cneg = -(c0 + c1);
    }

    // ---- per-iteration constants ----
    // znew = sgn*acc + (x + c5*t1 - su):
    //   lanes 0-15:  sgn=-1, c5=-0.5, su=-0.5*un
    //   lanes 16-31: sgn=+1, c5=-0.5, su=+0.5*un
    //   lanes 32-63: sgn=-1, c5=0,    su=0
    const float sgn = (lane >= 16 && lane < 32) ? 1.f : -1.f;
    const float c5  = (lane < 32) ? -0.5f : 0.f;
    const float su  = (lane < 32) ? 0.5f * sgn * un : 0.f;

    const int mi = *mi_ptr;
    const int nsteps = (MODE == 0) ? mi : ctl[0];

    const size_t zstride = (size_t)B * 64;
    const size_t zidx = (size_t)elem * 64 + lane;
    const float* zs_end = zstore + (size_t)zcap * zstride;   // uniform bound
    float* zs = zstore;                                       // uniform, SALU-bumped

    float z = 0.f;
    unsigned long long m0 = 0ull, m1 = 0ull, b0 = 1ull, b1 = 0ull;

    for (int k = 1; k <= nsteps; ++k) {
        float z16 = swz<SWZ_XOR16>(z);
        float x   = fmaxf(z, 0.f);
        float x16 = fmaxf(z16, 0.f);
        float t1  = x - x16;
        float vs  = (t1 - (z - z16)) + un;          // s, lanes 0-15 valid
        float vh  = fmaf(2.f, x, -z);               // h, lanes 32-63 valid

        float a0 = cneg, a1 = 0.f, a2 = 0.f, a3 = 0.f;
        MACS(a0, a1, a2, a3, vs, vh, W);
        float acc  = (a0 + a1) + (a2 + a3);         // lanes 0-31: At.w ; 32-63: w
        float znew = fmaf(sgn, acc, fmaf(c5, t1, x) - su);

        if (MODE == 0) {
            unsigned long long cy = b0 >> 63;
            b0 <<= 1; b1 = (b1 << 1) | cy;          // b = 1 << k (uniform, SALU)
            unsigned long long any = __ballot(fabsf(znew - z) >= TOL);
            if (any) { m0 |= b0; m1 |= b1; }
            if (zs < zs_end) zs[zidx] = znew;       // checkpoint step k -> slot k-1
            zs += zstride;
        }
        z = znew;
    }

    if (MODE == 0) {
        if (lane == 0) {
            int slot = blockIdx.x & 7;
            atomicOr(flags + 2 * slot,     m0);
            atomicOr(flags + 2 * slot + 1, m1);
        }
    } else {
        float z16b = swz<SWZ_XOR16>(z);
        if (lane < 16) out[(size_t)elem * 16 + lane] = z - z16b;
        out[(size_t)B * 16 + zidx] = z;
    }
}

// S = (first k in [1,mi) with global residual < TOL) + 1, else mi.
__global__ void dys_reduce(const int* __restrict__ mi_ptr,
                           const unsigned long long* __restrict__ flags,
                           int zcap, int* __restrict__ ctl)
{
    if (threadIdx.x != 0) return;
    unsigned long long m0 = 0ull, m1 = 0ull;
    for (int s = 0; s < 8; ++s) { m0 |= flags[2*s]; m1 |= flags[2*s+1]; }
    int mi = *mi_ptr;
    int S = mi;
    for (int k = 1; k < mi && k < 128; ++k) {
        unsigned long long bit = (k < 64) ? ((m0 >> k) & 1ull)
                                          : ((m1 >> (k - 64)) & 1ull);
        if (!bit) { S = k + 1; break; }
    }
    if (S < 1) S = 1;
    ctl[0] = S;
    ctl[1] = (S <= zcap) ? 1 : 0;
}

__global__ __launch_bounds__(256) void dys_gather(
    const int* __restrict__ ctl, const float* __restrict__ zstore,
    float* __restrict__ out, int B)
{
    if (!ctl[1]) return;
    int tid  = blockIdx.x * 256 + threadIdx.x;
    int lane = tid & 63;
    int elem = tid >> 6;
    int S = ctl[0];
    float z = zstore[(size_t)(S - 1) * B * 64 + (size_t)elem * 64 + lane];
    float z16 = swz<SWZ_XOR16>(z);
    if (lane < 16) out[(size_t)elem * 16 + lane] = z - z16;
    out[(size_t)B * 16 + (size_t)elem * 64 + lane] = z;
}

extern "C" void kernel_launch(void* const* d_in, const int* in_sizes, int n_in,
                              void* d_out, int out_size, void* d_ws, size_t ws_size,
                              hipStream_t stream) {
    (void)n_in; (void)out_size;
    const float* u_nom = (const float*)d_in[0];
    const float* Amat  = (const float*)d_in[1];
    const float* bvec  = (const float*)d_in[2];
    const int*   mi    = (const int*)d_in[3];

    const int B = in_sizes[0] / 16;                  // 8192

    unsigned long long* flags = (unsigned long long*)d_ws;
    int* ctl = (int*)((char*)d_ws + WS_CTL_OFF);
    float* zstore = (float*)((char*)d_ws + WS_Z_OFF);

    const size_t stepBytes = (size_t)B * 64 * sizeof(float);   // 2 MB
    int zcap = 0;
    if (ws_size > WS_Z_OFF + stepBytes)
        zcap = (int)((ws_size - WS_Z_OFF) / stepBytes);
    if (zcap > 127) zcap = 127;                      // masks cover k < 128

    hipMemsetAsync(d_ws, 0, 256, stream);            // flags + ctl

    const int blocks = B / WPB;
    dys_pass<0><<<blocks, 64 * WPB, 0, stream>>>(u_nom, Amat, bvec, mi, ctl,
                                                 flags, zstore, zcap, (float*)d_out, B);
    dys_reduce<<<1, 64, 0, stream>>>(mi, flags, zcap, ctl);
    // Fallback replay (early-exits when checkpoints cover S):
    dys_pass<1><<<blocks, 64 * WPB, 0, stream>>>(u_nom, Amat, bvec, mi, ctl,
                                                 flags, zstore, zcap, (float*)d_out, B);
    // Checkpoint gather (early-exits when fallback ran):
    dys_gather<<<B * 64 / 256, 256, 0, stream>>>(ctl, zstore, (float*)d_out, B);
}

// Round 9
// 342.603 us; speedup vs baseline: 1.0295x; 1.0295x over previous
//
#include <hip/hip_runtime.h>
#include <stdint.h>

#define TOL 1e-2f
#define WPB 4
// ws layout: [0..128): 8 hashed flag slots (2 u64 each); [192..200): ctl {S, k0};
// [4096 .. 4096+B*9408): W area (per elem: 48 rows x 12 float4 + 48 cneg);
// [zoff ..): z checkpoints for even k, 2 MB per slot.
#define WS_CTL_OFF 192
#define WS_W_OFF   4096
#define W_STRIDE_F 2352          // floats per element: 2304 row data + 48 cneg

__device__ __forceinline__ float bcastf(float v, int l) {
    return __int_as_float(__builtin_amdgcn_readlane(__float_as_int(v), l));
}
template <int PAT>
__device__ __forceinline__ float swz(float v) {
    return __int_as_float(__builtin_amdgcn_ds_swizzle(__float_as_int(v), PAT));
}
#define SWZ_XOR16 0x401F   // src = lane ^ 16

// 48-MAC broadcast matvec, fully pinned: W in arch VGPRs, readlane->SGPR
// software-pipelined depth-3 (covers VALU->SGPR->VALU wait states).
// Proven correct in R8.
#define MACS(a0,a1,a2,a3,vs,vh,Wp) \
  asm("s_nop 1\n\t" \
      "v_readlane_b32 s20, %[vs], 0\n\t" \
      "v_readlane_b32 s21, %[vs], 1\n\t" \
      "v_readlane_b32 s22, %[vs], 2\n\t" \
      "v_fmac_f32 %[a0], s20, %[w0]\n\t"  "v_readlane_b32 s20, %[vs], 3\n\t" \
      "v_fmac_f32 %[a1], s21, %[w1]\n\t"  "v_readlane_b32 s21, %[vs], 4\n\t" \
      "v_fmac_f32 %[a2], s22, %[w2]\n\t"  "v_readlane_b32 s22, %[vs], 5\n\t" \
      "v_fmac_f32 %[a3], s20, %[w3]\n\t"  "v_readlane_b32 s20, %[vs], 6\n\t" \
      "v_fmac_f32 %[a0], s21, %[w4]\n\t"  "v_readlane_b32 s21, %[vs], 7\n\t" \
      "v_fmac_f32 %[a1], s22, %[w5]\n\t"  "v_readlane_b32 s22, %[vs], 8\n\t" \
      "v_fmac_f32 %[a2], s20, %[w6]\n\t"  "v_readlane_b32 s20, %[vs], 9\n\t" \
      "v_fmac_f32 %[a3], s21, %[w7]\n\t"  "v_readlane_b32 s21, %[vs], 10\n\t" \
      "v_fmac_f32 %[a0], s22, %[w8]\n\t"  "v_readlane_b32 s22, %[vs], 11\n\t" \
      "v_fmac_f32 %[a1], s20, %[w9]\n\t"  "v_readlane_b32 s20, %[vs], 12\n\t" \
      "v_fmac_f32 %[a2], s21, %[w10]\n\t" "v_readlane_b32 s21, %[vs], 13\n\t" \
      "v_fmac_f32 %[a3], s22, %[w11]\n\t" "v_readlane_b32 s22, %[vs], 14\n\t" \
      "v_fmac_f32 %[a0], s20, %[w12]\n\t" "v_readlane_b32 s20, %[vs], 15\n\t" \
      "v_fmac_f32 %[a1], s21, %[w13]\n\t" "v_readlane_b32 s21, %[vh], 32\n\t" \
      "v_fmac_f32 %[a2], s22, %[w14]\n\t" "v_readlane_b32 s22, %[vh], 33\n\t" \
      "v_fmac_f32 %[a3], s20, %[w15]\n\t" "v_readlane_b32 s20, %[vh], 34\n\t" \
      "v_fmac_f32 %[a0], s21, %[w16]\n\t" "v_readlane_b32 s21, %[vh], 35\n\t" \
      "v_fmac_f32 %[a1], s22, %[w17]\n\t" "v_readlane_b32 s22, %[vh], 36\n\t" \
      "v_fmac_f32 %[a2], s20, %[w18]\n\t" "v_readlane_b32 s20, %[vh], 37\n\t" \
      "v_fmac_f32 %[a3], s21, %[w19]\n\t" "v_readlane_b32 s21, %[vh], 38\n\t" \
      "v_fmac_f32 %[a0], s22, %[w20]\n\t" "v_readlane_b32 s22, %[vh], 39\n\t" \
      "v_fmac_f32 %[a1], s20, %[w21]\n\t" "v_readlane_b32 s20, %[vh], 40\n\t" \
      "v_fmac_f32 %[a2], s21, %[w22]\n\t" "v_readlane_b32 s21, %[vh], 41\n\t" \
      "v_fmac_f32 %[a3], s22, %[w23]\n\t" "v_readlane_b32 s22, %[vh], 42\n\t" \
      "v_fmac_f32 %[a0], s20, %[w24]\n\t" "v_readlane_b32 s20, %[vh], 43\n\t" \
      "v_fmac_f32 %[a1], s21, %[w25]\n\t" "v_readlane_b32 s21, %[vh], 44\n\t" \
      "v_fmac_f32 %[a2], s22, %[w26]\n\t" "v_readlane_b32 s22, %[vh], 45\n\t" \
      "v_fmac_f32 %[a3], s20, %[w27]\n\t" "v_readlane_b32 s20, %[vh], 46\n\t" \
      "v_fmac_f32 %[a0], s21, %[w28]\n\t" "v_readlane_b32 s21, %[vh], 47\n\t" \
      "v_fmac_f32 %[a1], s22, %[w29]\n\t" "v_readlane_b32 s22, %[vh], 48\n\t" \
      "v_fmac_f32 %[a2], s20, %[w30]\n\t" "v_readlane_b32 s20, %[vh], 49\n\t" \
      "v_fmac_f32 %[a3], s21, %[w31]\n\t" "v_readlane_b32 s21, %[vh], 50\n\t" \
      "v_fmac_f32 %[a0], s22, %[w32]\n\t" "v_readlane_b32 s22, %[vh], 51\n\t" \
      "v_fmac_f32 %[a1], s20, %[w33]\n\t" "v_readlane_b32 s20, %[vh], 52\n\t" \
      "v_fmac_f32 %[a2], s21, %[w34]\n\t" "v_readlane_b32 s21, %[vh], 53\n\t" \
      "v_fmac_f32 %[a3], s22, %[w35]\n\t" "v_readlane_b32 s22, %[vh], 54\n\t" \
      "v_fmac_f32 %[a0], s20, %[w36]\n\t" "v_readlane_b32 s20, %[vh], 55\n\t" \
      "v_fmac_f32 %[a1], s21, %[w37]\n\t" "v_readlane_b32 s21, %[vh], 56\n\t" \
      "v_fmac_f32 %[a2], s22, %[w38]\n\t" "v_readlane_b32 s22, %[vh], 57\n\t" \
      "v_fmac_f32 %[a3], s20, %[w39]\n\t" "v_readlane_b32 s20, %[vh], 58\n\t" \
      "v_fmac_f32 %[a0], s21, %[w40]\n\t" "v_readlane_b32 s21, %[vh], 59\n\t" \
      "v_fmac_f32 %[a1], s22, %[w41]\n\t" "v_readlane_b32 s22, %[vh], 60\n\t" \
      "v_fmac_f32 %[a2], s20, %[w42]\n\t" "v_readlane_b32 s20, %[vh], 61\n\t" \
      "v_fmac_f32 %[a3], s21, %[w43]\n\t" "v_readlane_b32 s21, %[vh], 62\n\t" \
      "v_fmac_f32 %[a0], s22, %[w44]\n\t" "v_readlane_b32 s22, %[vh], 63\n\t" \
      "v_fmac_f32 %[a1], s20, %[w45]\n\t" \
      "v_fmac_f32 %[a2], s21, %[w46]\n\t" \
      "v_fmac_f32 %[a3], s22, %[w47]\n\t" \
      : [a0]"+v"(a0), [a1]"+v"(a1), [a2]"+v"(a2), [a3]"+v"(a3) \
      : [vs]"v"(vs), [vh]"v"(vh), \
        [w0]"v"(Wp[0]),  [w1]"v"(Wp[1]),  [w2]"v"(Wp[2]),  [w3]"v"(Wp[3]), \
        [w4]"v"(Wp[4]),  [w5]"v"(Wp[5]),  [w6]"v"(Wp[6]),  [w7]"v"(Wp[7]), \
        [w8]"v"(Wp[8]),  [w9]"v"(Wp[9]),  [w10]"v"(Wp[10]),[w11]"v"(Wp[11]), \
        [w12]"v"(Wp[12]),[w13]"v"(Wp[13]),[w14]"v"(Wp[14]),[w15]"v"(Wp[15]), \
        [w16]"v"(Wp[16]),[w17]"v"(Wp[17]),[w18]"v"(Wp[18]),[w19]"v"(Wp[19]), \
        [w20]"v"(Wp[20]),[w21]"v"(Wp[21]),[w22]"v"(Wp[22]),[w23]"v"(Wp[23]), \
        [w24]"v"(Wp[24]),[w25]"v"(Wp[25]),[w26]"v"(Wp[26]),[w27]"v"(Wp[27]), \
        [w28]"v"(Wp[28]),[w29]"v"(Wp[29]),[w30]"v"(Wp[30]),[w31]"v"(Wp[31]), \
        [w32]"v"(Wp[32]),[w33]"v"(Wp[33]),[w34]"v"(Wp[34]),[w35]"v"(Wp[35]), \
        [w36]"v"(Wp[36]),[w37]"v"(Wp[37]),[w38]"v"(Wp[38]),[w39]"v"(Wp[39]), \
        [w40]"v"(Wp[40]),[w41]"v"(Wp[41]),[w42]"v"(Wp[42]),[w43]"v"(Wp[43]), \
        [w44]"v"(Wp[44]),[w45]"v"(Wp[45]),[w46]"v"(Wp[46]),[w47]"v"(Wp[47]) \
      : "s20", "s21", "s22")

// C++ fallback step (finisher only; proven in R6).
__device__ __forceinline__ float dys_step(float z, const float* __restrict__ W,
                                          float cneg, float un, float nun,
                                          float sgn, float sgn0, int lane) {
    float z16 = swz<SWZ_XOR16>(z);
    float x   = fmaxf(z, 0.f);
    float x16 = fmaxf(z16, 0.f);
    float t1  = x - x16;
    float s   = (t1 - (z - z16)) + un;
    float h   = fmaf(2.f, x, -z);
    float ee  = fmaf(sgn0, t1, nun);
    float a0 = cneg, a1 = 0.f, a2 = 0.f, a3 = 0.f;
    #pragma unroll
    for (int m = 0; m < 16; m += 4) {
        a0 = fmaf(W[m],     bcastf(s, m),     a0);
        a1 = fmaf(W[m + 1], bcastf(s, m + 1), a1);
        a2 = fmaf(W[m + 2], bcastf(s, m + 2), a2);
        a3 = fmaf(W[m + 3], bcastf(s, m + 3), a3);
    }
    #pragma unroll
    for (int m = 0; m < 32; m += 4) {
        a0 = fmaf(W[16 + m], bcastf(h, 32 + m), a0);
        a1 = fmaf(W[17 + m], bcastf(h, 33 + m), a1);
        a2 = fmaf(W[18 + m], bcastf(h, 34 + m), a2);
        a3 = fmaf(W[19 + m], bcastf(h, 35 + m), a3);
    }
    float acc = (a0 + a1) + (a2 + a3);
    float t   = (lane < 32) ? fmaf(0.5f, ee, acc) : acc;
    return fmaf(sgn, t, x);
}

__device__ __forceinline__ void load_W(const float* __restrict__ eb, int lane,
                                       float* __restrict__ W, float* cneg) {
    const int col16 = lane & 15;
    const int R = (lane < 32) ? col16 : (lane - 16);   // storage row index
    const float4* Wv = (const float4*)eb;
    #pragma unroll
    for (int q = 0; q < 12; ++q) {
        float4 v = Wv[q * 48 + R];
        W[4*q] = v.x; W[4*q+1] = v.y; W[4*q+2] = v.z; W[4*q+3] = v.w;
    }
    *cneg = eb[2304 + R];
}

// ---------------- setup: build W rows + per-row constant, store to ws ----------------
__global__ __launch_bounds__(256) void dys_setup(
    const float* __restrict__ Amat,      // (B,32,16)
    const float* __restrict__ bvec,      // (B,32)
    float*       __restrict__ wws,
    int B)
{
    const int tid   = threadIdx.x;
    const int lane  = tid & 63;
    const int wib   = tid >> 6;
    const int elem  = blockIdx.x * WPB + wib;
    const int row32 = lane & 31;
    const int col16 = lane & 15;

    __shared__ __align__(16) float ldsT[WPB][32 * 17];
    float* T = ldsT[wib];      // wave-private; lgkmcnt ordering, no __syncthreads

    const float* Ab = Amat + (size_t)elem * 512 + (size_t)row32 * 16;
    float A_row[16];
    {
        float4 a0 = ((const float4*)Ab)[0];
        float4 a1 = ((const float4*)Ab)[1];
        float4 a2 = ((const float4*)Ab)[2];
        float4 a3 = ((const float4*)Ab)[3];
        A_row[0]=a0.x;  A_row[1]=a0.y;  A_row[2]=a0.z;  A_row[3]=a0.w;
        A_row[4]=a1.x;  A_row[5]=a1.y;  A_row[6]=a1.z;  A_row[7]=a1.w;
        A_row[8]=a2.x;  A_row[9]=a2.y;  A_row[10]=a2.z; A_row[11]=a2.w;
        A_row[12]=a3.x; A_row[13]=a3.y; A_row[14]=a3.z; A_row[15]=a3.w;
    }
    if (lane < 32) {
        #pragma unroll
        for (int k = 0; k < 16; ++k) T[row32 * 17 + k] = A_row[k];
    }
    const float bv = bvec[(size_t)elem * 32 + row32];

    float W[48];

    // N = 2*A*A^T + I, row (lane&31)
    {
        float A2[16];
        #pragma unroll
        for (int k = 0; k < 16; ++k) A2[k] = A_row[k] + A_row[k];
        #pragma unroll
        for (int j = 0; j < 32; ++j) {
            float acc = (row32 == j) ? 1.f : 0.f;
            #pragma unroll
            for (int k = 0; k < 16; ++k)
                acc = fmaf(A2[k], bcastf(A_row[k], j), acc);
            W[16 + j] = acc;
        }
    }

    // in-place Gauss-Jordan: W[16..47] -> Q = N^-1 row (lane&31)
    #pragma unroll
    for (int p = 0; p < 32; ++p) {
        float piv = bcastf(W[16 + p], p);
        float d = __builtin_amdgcn_rcpf(piv);
        d = d * (2.f - piv * d);
        float g = W[16 + p] * d;
        g = (row32 == p) ? (1.f - d) : g;
        float negg = -g;
        #pragma unroll
        for (int j = 0; j < 32; ++j) {
            if (j == p) continue;
            float spj = bcastf(W[16 + j], p);
            W[16 + j] = fmaf(negg, spj, W[16 + j]);
        }
        W[16 + p] = (row32 == p) ? d : negg;
    }

    // QA row (lane&31) into W[0..15]
    #pragma unroll
    for (int k = 0; k < 16; ++k) W[k] = 0.f;
    #pragma unroll
    for (int m = 0; m < 32; ++m) {
        float q = W[16 + m];
        #pragma unroll
        for (int k = 0; k < 16; ++k)
            W[k] = fmaf(q, bcastf(A_row[k], m), W[k]);
    }

    // lanes 0-31: AtQA row i (A staged in T, QA row broadcasts)
    float tq[16];
    #pragma unroll
    for (int k = 0; k < 16; ++k) tq[k] = 0.f;
    #pragma unroll
    for (int m = 0; m < 32; ++m) {
        float a_mi = T[m * 17 + col16];
        #pragma unroll
        for (int k = 0; k < 16; ++k)
            tq[k] = fmaf(a_mi, bcastf(W[k], m), tq[k]);
    }

    if (lane < 32) {
        #pragma unroll
        for (int k = 0; k < 16; ++k) T[row32 * 17 + k] = W[k];   // stage QA rows
    }
    if (lane < 32) {
        #pragma unroll
        for (int m = 0; m < 32; ++m) W[16 + m] = T[m * 17 + col16];  // AtQ[i][m]
        #pragma unroll
        for (int k = 0; k < 16; ++k) W[k] = tq[k];                   // AtQA row i
    }

    // per-row constant c = (lanes<32 ? AtQ.b : Q.b); store -c
    float cneg;
    {
        float c0 = 0.f, c1 = 0.f;
        #pragma unroll
        for (int m = 0; m < 32; m += 2) {
            c0 = fmaf(W[16 + m], bcastf(bv, m),     c0);
            c1 = fmaf(W[17 + m], bcastf(bv, m + 1), c1);
        }
        cneg = -(c0 + c1);
    }

    // store: rows 0-15 from lanes 0-15, rows 16-47 from lanes 32-63
    float* eb = wws + (size_t)elem * W_STRIDE_F;
    if (lane < 16 || lane >= 32) {
        const int R = (lane < 16) ? lane : (lane - 16);
        float4* dst = (float4*)eb;
        #pragma unroll
        for (int q = 0; q < 12; ++q) {
            float4 v;
            v.x = W[4*q]; v.y = W[4*q+1]; v.z = W[4*q+2]; v.w = W[4*q+3];
            dst[q * 48 + R] = v;
        }
        eb[2304 + R] = cneg;
    }
}

// ---------------- loop: mi steps, asm MACS core, masks + even-k checkpoints ----------------
__global__ __launch_bounds__(256) void dys_loop(
    const float* __restrict__ u_nom,
    const int*   __restrict__ mi_ptr,
    const float* __restrict__ wws,
    unsigned long long* __restrict__ flags,
    float*       __restrict__ zstore,
    int zcap, int B)
{
    const int tid  = threadIdx.x;
    const int lane = tid & 63;
    const int wib  = tid >> 6;
    const int elem = blockIdx.x * WPB + wib;
    const int col16 = lane & 15;

    float W[48], cneg;
    load_W(wws + (size_t)elem * W_STRIDE_F, lane, W, &cneg);

    const float un  = u_nom[(size_t)elem * 16 + col16];
    // znew = sgn*acc + (x + c5*t1 - su)
    const float sgn = (lane >= 16 && lane < 32) ? 1.f : -1.f;
    const float c5  = (lane < 32) ? -0.5f : 0.f;
    const float su  = (lane < 32) ? 0.5f * sgn * un : 0.f;

    const int mi = *mi_ptr;
    const size_t zstride = (size_t)B * 64;
    const size_t zidx = (size_t)elem * 64 + lane;

    float z = 0.f;
    unsigned long long m0 = 0ull, m1 = 0ull, b0 = 1ull, b1 = 0ull;

    for (int k = 1; k <= mi; ++k) {
        float z16 = swz<SWZ_XOR16>(z);
        float x   = fmaxf(z, 0.f);
        float x16 = fmaxf(z16, 0.f);
        float t1  = x - x16;
        float vs  = (t1 - (z - z16)) + un;          // s, lanes 0-15 valid
        float vh  = fmaf(2.f, x, -z);               // h, lanes 32-63 valid

        float a0 = cneg, a1 = 0.f, a2 = 0.f, a3 = 0.f;
        MACS(a0, a1, a2, a3, vs, vh, W);
        float acc  = (a0 + a1) + (a2 + a3);
        float znew = fmaf(sgn, acc, fmaf(c5, t1, x) - su);

        unsigned long long cy = b0 >> 63;
        b0 <<= 1; b1 = (b1 << 1) | cy;              // b = 1 << k (uniform, SALU)
        unsigned long long any = __ballot(fabsf(znew - z) >= TOL);
        if (any) { m0 |= b0; m1 |= b1; }

        if (!(k & 1)) {                             // checkpoint even k
            int slot = k >> 1;                      // >= 1
            if (slot <= zcap)
                zstore[(size_t)(slot - 1) * zstride + zidx] = znew;
        }
        z = znew;
    }

    if (lane == 0) {
        int slot = blockIdx.x & 7;
        atomicOr(flags + 2 * slot,     m0);
        atomicOr(flags + 2 * slot + 1, m1);
    }
}

// S = (first k in [1,mi) with global residual < TOL) + 1, else mi. k0 = even start.
__global__ void dys_reduce(const int* __restrict__ mi_ptr,
                           const unsigned long long* __restrict__ flags,
                           int zcap, int* __restrict__ ctl)
{
    if (threadIdx.x != 0) return;
    unsigned long long m0 = 0ull, m1 = 0ull;
    for (int s = 0; s < 8; ++s) { m0 |= flags[2*s]; m1 |= flags[2*s+1]; }
    int mi = *mi_ptr;
    int S = mi;
    for (int k = 1; k < mi && k < 128; ++k) {
        unsigned long long bit = (k < 64) ? ((m0 >> k) & 1ull)
                                          : ((m1 >> (k - 64)) & 1ull);
        if (!bit) { S = k + 1; break; }
    }
    if (S < 1) S = 1;
    int k0 = S & ~1;                    // largest even <= S
    int kmax = 2 * zcap;
    if (k0 > kmax) k0 = kmax;
    ctl[0] = S;
    ctl[1] = k0;
}

// ---------------- finisher: resume from checkpoint k0, run S-k0 steps, emit ----------------
__global__ __launch_bounds__(256) void dys_finish(
    const float* __restrict__ u_nom,
    const float* __restrict__ wws,
    const int*   __restrict__ ctl,
    const float* __restrict__ zstore,
    float*       __restrict__ out,
    int B)
{
    const int tid  = threadIdx.x;
    const int lane = tid & 63;
    const int wib  = tid >> 6;
    const int elem = blockIdx.x * WPB + wib;
    const int col16 = lane & 15;

    const int S  = ctl[0];
    const int k0 = ctl[1];
    const size_t zidx = (size_t)elem * 64 + lane;

    float z = 0.f;
    if (k0 > 0)
        z = zstore[(size_t)(k0 / 2 - 1) * ((size_t)B * 64) + zidx];

    int rem = S - k0;
    if (rem > 0) {
        float W[48], cneg;
        load_W(wws + (size_t)elem * W_STRIDE_F, lane, W, &cneg);
        const float un   = u_nom[(size_t)elem * 16 + col16];
        const float nun  = -un;
        const float sgn  = (lane >= 16 && lane < 32) ? 1.f : -1.f;
        const float sgn0 = (lane & 16) ? -1.f : 1.f;
        for (int r = 0; r < rem; ++r)
            z = dys_step(z, W, cneg, un, nun, sgn, sgn0, lane);
    }

    float z16b = swz<SWZ_XOR16>(z);
    if (lane < 16) out[(size_t)elem * 16 + lane] = z - z16b;   // u_star
    out[(size_t)B * 16 + zidx] = z;                             // z_star
}

extern "C" void kernel_launch(void* const* d_in, const int* in_sizes, int n_in,
                              void* d_out, int out_size, void* d_ws, size_t ws_size,
                              hipStream_t stream) {
    (void)n_in; (void)out_size;
    const float* u_nom = (const float*)d_in[0];
    const float* Amat  = (const float*)d_in[1];
    const float* bvec  = (const float*)d_in[2];
    const int*   mi    = (const int*)d_in[3];

    const int B = in_sizes[0] / 16;                  // 8192

    unsigned long long* flags = (unsigned long long*)d_ws;
    int* ctl = (int*)((char*)d_ws + WS_CTL_OFF);
    float* wws = (float*)((char*)d_ws + WS_W_OFF);

    const size_t wbytes = (size_t)B * W_STRIDE_F * sizeof(float);   // ~77 MB
    const size_t zoff = WS_W_OFF + wbytes;
    float* zstore = (float*)((char*)d_ws + zoff);

    const size_t stepBytes = (size_t)B * 64 * sizeof(float);        // 2 MB
    int zcap = 0;
    if (ws_size > zoff + stepBytes)
        zcap = (int)((ws_size - zoff) / stepBytes);
    if (zcap > 63) zcap = 63;                        // masks cover k < 128

    hipMemsetAsync(d_ws, 0, 256, stream);            // flags + ctl

    const int blocks = B / WPB;
    dys_setup <<<blocks, 64 * WPB, 0, stream>>>(Amat, bvec, wws, B);
    dys_loop  <<<blocks, 64 * WPB, 0, stream>>>(u_nom, mi, wws, flags, zstore, zcap, B);
    dys_reduce<<<1, 64, 0, stream>>>(mi, flags, zcap, ctl);
    dys_finish<<<blocks, 64 * WPB, 0, stream>>>(u_nom, wws, ctl, zstore,
                                                (float*)d_out, B);
}

// Round 10
// 302.482 us; speedup vs baseline: 1.1660x; 1.1326x over previous
//
#include <hip/hip_runtime.h>
#include <stdint.h>

#define TOL 1e-2f
#define WPB 4
// ws layout: [0..128): 8 hashed flag slots (2 u64 each); [192..200): ctl {S, ok};
// [4096 ..): z checkpoints, one 2 MB slab per step k (slot k-1).
#define WS_CTL_OFF 192
#define WS_Z_OFF   4096

__device__ __forceinline__ float bcastf(float v, int l) {
    return __int_as_float(__builtin_amdgcn_readlane(__float_as_int(v), l));
}
template <int PAT>
__device__ __forceinline__ float swz(float v) {
    return __int_as_float(__builtin_amdgcn_ds_swizzle(__float_as_int(v), PAT));
}
#define SWZ_XOR16 0x401F   // src = lane ^ 16

// 48-MAC broadcast matvec, pinned; proven correct in R8/R9.
#define MACS(a0,a1,a2,a3,vs,vh,Wp) \
  asm("s_nop 1\n\t" \
      "v_readlane_b32 s20, %[vs], 0\n\t" \
      "v_readlane_b32 s21, %[vs], 1\n\t" \
      "v_readlane_b32 s22, %[vs], 2\n\t" \
      "v_fmac_f32 %[a0], s20, %[w0]\n\t"  "v_readlane_b32 s20, %[vs], 3\n\t" \
      "v_fmac_f32 %[a1], s21, %[w1]\n\t"  "v_readlane_b32 s21, %[vs], 4\n\t" \
      "v_fmac_f32 %[a2], s22, %[w2]\n\t"  "v_readlane_b32 s22, %[vs], 5\n\t" \
      "v_fmac_f32 %[a3], s20, %[w3]\n\t"  "v_readlane_b32 s20, %[vs], 6\n\t" \
      "v_fmac_f32 %[a0], s21, %[w4]\n\t"  "v_readlane_b32 s21, %[vs], 7\n\t" \
      "v_fmac_f32 %[a1], s22, %[w5]\n\t"  "v_readlane_b32 s22, %[vs], 8\n\t" \
      "v_fmac_f32 %[a2], s20, %[w6]\n\t"  "v_readlane_b32 s20, %[vs], 9\n\t" \
      "v_fmac_f32 %[a3], s21, %[w7]\n\t"  "v_readlane_b32 s21, %[vs], 10\n\t" \
      "v_fmac_f32 %[a0], s22, %[w8]\n\t"  "v_readlane_b32 s22, %[vs], 11\n\t" \
      "v_fmac_f32 %[a1], s20, %[w9]\n\t"  "v_readlane_b32 s20, %[vs], 12\n\t" \
      "v_fmac_f32 %[a2], s21, %[w10]\n\t" "v_readlane_b32 s21, %[vs], 13\n\t" \
      "v_fmac_f32 %[a3], s22, %[w11]\n\t" "v_readlane_b32 s22, %[vs], 14\n\t" \
      "v_fmac_f32 %[a0], s20, %[w12]\n\t" "v_readlane_b32 s20, %[vs], 15\n\t" \
      "v_fmac_f32 %[a1], s21, %[w13]\n\t" "v_readlane_b32 s21, %[vh], 32\n\t" \
      "v_fmac_f32 %[a2], s22, %[w14]\n\t" "v_readlane_b32 s22, %[vh], 33\n\t" \
      "v_fmac_f32 %[a3], s20, %[w15]\n\t" "v_readlane_b32 s20, %[vh], 34\n\t" \
      "v_fmac_f32 %[a0], s21, %[w16]\n\t" "v_readlane_b32 s21, %[vh], 35\n\t" \
      "v_fmac_f32 %[a1], s22, %[w17]\n\t" "v_readlane_b32 s22, %[vh], 36\n\t" \
      "v_fmac_f32 %[a2], s20, %[w18]\n\t" "v_readlane_b32 s20, %[vh], 37\n\t" \
      "v_fmac_f32 %[a3], s21, %[w19]\n\t" "v_readlane_b32 s21, %[vh], 38\n\t" \
      "v_fmac_f32 %[a0], s22, %[w20]\n\t" "v_readlane_b32 s22, %[vh], 39\n\t" \
      "v_fmac_f32 %[a1], s20, %[w21]\n\t" "v_readlane_b32 s20, %[vh], 40\n\t" \
      "v_fmac_f32 %[a2], s21, %[w22]\n\t" "v_readlane_b32 s21, %[vh], 41\n\t" \
      "v_fmac_f32 %[a3], s22, %[w23]\n\t" "v_readlane_b32 s22, %[vh], 42\n\t" \
      "v_fmac_f32 %[a0], s20, %[w24]\n\t" "v_readlane_b32 s20, %[vh], 43\n\t" \
      "v_fmac_f32 %[a1], s21, %[w25]\n\t" "v_readlane_b32 s21, %[vh], 44\n\t" \
      "v_fmac_f32 %[a2], s22, %[w26]\n\t" "v_readlane_b32 s22, %[vh], 45\n\t" \
      "v_fmac_f32 %[a3], s20, %[w27]\n\t" "v_readlane_b32 s20, %[vh], 46\n\t" \
      "v_fmac_f32 %[a0], s21, %[w28]\n\t" "v_readlane_b32 s21, %[vh], 47\n\t" \
      "v_fmac_f32 %[a1], s22, %[w29]\n\t" "v_readlane_b32 s22, %[vh], 48\n\t" \
      "v_fmac_f32 %[a2], s20, %[w30]\n\t" "v_readlane_b32 s20, %[vh], 49\n\t" \
      "v_fmac_f32 %[a3], s21, %[w31]\n\t" "v_readlane_b32 s21, %[vh], 50\n\t" \
      "v_fmac_f32 %[a0], s22, %[w32]\n\t" "v_readlane_b32 s22, %[vh], 51\n\t" \
      "v_fmac_f32 %[a1], s20, %[w33]\n\t" "v_readlane_b32 s20, %[vh], 52\n\t" \
      "v_fmac_f32 %[a2], s21, %[w34]\n\t" "v_readlane_b32 s21, %[vh], 53\n\t" \
      "v_fmac_f32 %[a3], s22, %[w35]\n\t" "v_readlane_b32 s22, %[vh], 54\n\t" \
      "v_fmac_f32 %[a0], s20, %[w36]\n\t" "v_readlane_b32 s20, %[vh], 55\n\t" \
      "v_fmac_f32 %[a1], s21, %[w37]\n\t" "v_readlane_b32 s21, %[vh], 56\n\t" \
      "v_fmac_f32 %[a2], s22, %[w38]\n\t" "v_readlane_b32 s22, %[vh], 57\n\t" \
      "v_fmac_f32 %[a3], s20, %[w39]\n\t" "v_readlane_b32 s20, %[vh], 58\n\t" \
      "v_fmac_f32 %[a0], s21, %[w40]\n\t" "v_readlane_b32 s21, %[vh], 59\n\t" \
      "v_fmac_f32 %[a1], s22, %[w41]\n\t" "v_readlane_b32 s22, %[vh], 60\n\t" \
      "v_fmac_f32 %[a2], s20, %[w42]\n\t" "v_readlane_b32 s20, %[vh], 61\n\t" \
      "v_fmac_f32 %[a3], s21, %[w43]\n\t" "v_readlane_b32 s21, %[vh], 62\n\t" \
      "v_fmac_f32 %[a0], s22, %[w44]\n\t" "v_readlane_b32 s22, %[vh], 63\n\t" \
      "v_fmac_f32 %[a1], s20, %[w45]\n\t" \
      "v_fmac_f32 %[a2], s21, %[w46]\n\t" \
      "v_fmac_f32 %[a3], s22, %[w47]\n\t" \
      : [a0]"+v"(a0), [a1]"+v"(a1), [a2]"+v"(a2), [a3]"+v"(a3) \
      : [vs]"v"(vs), [vh]"v"(vh), \
        [w0]"v"(Wp[0]),  [w1]"v"(Wp[1]),  [w2]"v"(Wp[2]),  [w3]"v"(Wp[3]), \
        [w4]"v"(Wp[4]),  [w5]"v"(Wp[5]),  [w6]"v"(Wp[6]),  [w7]"v"(Wp[7]), \
        [w8]"v"(Wp[8]),  [w9]"v"(Wp[9]),  [w10]"v"(Wp[10]),[w11]"v"(Wp[11]), \
        [w12]"v"(Wp[12]),[w13]"v"(Wp[13]),[w14]"v"(Wp[14]),[w15]"v"(Wp[15]), \
        [w16]"v"(Wp[16]),[w17]"v"(Wp[17]),[w18]"v"(Wp[18]),[w19]"v"(Wp[19]), \
        [w20]"v"(Wp[20]),[w21]"v"(Wp[21]),[w22]"v"(Wp[22]),[w23]"v"(Wp[23]), \
        [w24]"v"(Wp[24]),[w25]"v"(Wp[25]),[w26]"v"(Wp[26]),[w27]"v"(Wp[27]), \
        [w28]"v"(Wp[28]),[w29]"v"(Wp[29]),[w30]"v"(Wp[30]),[w31]"v"(Wp[31]), \
        [w32]"v"(Wp[32]),[w33]"v"(Wp[33]),[w34]"v"(Wp[34]),[w35]"v"(Wp[35]), \
        [w36]"v"(Wp[36]),[w37]"v"(Wp[37]),[w38]"v"(Wp[38]),[w39]"v"(Wp[39]), \
        [w40]"v"(Wp[40]),[w41]"v"(Wp[41]),[w42]"v"(Wp[42]),[w43]"v"(Wp[43]), \
        [w44]"v"(Wp[44]),[w45]"v"(Wp[45]),[w46]"v"(Wp[46]),[w47]"v"(Wp[47]) \
      : "s20", "s21", "s22")

// MODE 0: run mi steps; checkpoint every step; record per-step residual bits.
// MODE 1: fallback replay (only if ctl[1]==0): run ctl[0] steps, write out.
template <int MODE>
__global__ __launch_bounds__(256) void dys_pass(
    const float* __restrict__ u_nom,     // (B,16)
    const float* __restrict__ Amat,      // (B,32,16)
    const float* __restrict__ bvec,      // (B,32)
    const int*   __restrict__ mi_ptr,
    const int*   __restrict__ ctl,       // {S, stored_ok}
    unsigned long long* __restrict__ flags,
    float*       __restrict__ zstore,
    int zcap,
    float*       __restrict__ out,
    int B)
{
    if (MODE == 1) { if (ctl[1]) return; }

    const int tid   = threadIdx.x;
    const int lane  = tid & 63;
    const int wib   = tid >> 6;
    const int elem  = blockIdx.x * WPB + wib;
    const int row32 = lane & 31;
    const int col16 = lane & 15;

    // Wave-private LDS: A16 = XOR-swizzled A (uniform b128 streams, conflict-free);
    // QAT = stride-17 buffer for the QA transpose. Same-wave ordering via lgkmcnt.
    __shared__ __align__(16) float ldsA[WPB][512];
    __shared__ float ldsQ[WPB][32 * 17];
    float* A16 = ldsA[wib];
    float* QAT = ldsQ[wib];
    const float4* Av = (const float4*)A16;

    // ---- load A row; stage XOR-swizzled into A16 (lanes<32) ----
    const float* Ab = Amat + (size_t)elem * 512 + (size_t)row32 * 16;
    float A_row[16];
    {
        float4 a0 = ((const float4*)Ab)[0];
        float4 a1 = ((const float4*)Ab)[1];
        float4 a2 = ((const float4*)Ab)[2];
        float4 a3 = ((const float4*)Ab)[3];
        A_row[0]=a0.x;  A_row[1]=a0.y;  A_row[2]=a0.z;  A_row[3]=a0.w;
        A_row[4]=a1.x;  A_row[5]=a1.y;  A_row[6]=a1.z;  A_row[7]=a1.w;
        A_row[8]=a2.x;  A_row[9]=a2.y;  A_row[10]=a2.z; A_row[11]=a2.w;
        A_row[12]=a3.x; A_row[13]=a3.y; A_row[14]=a3.z; A_row[15]=a3.w;
    }
    if (lane < 32) {
        #pragma unroll
        for (int k = 0; k < 16; ++k)
            A16[row32 * 16 + ((((k >> 2) ^ (row32 & 3)) << 2) | (k & 3))] = A_row[k];
    }
    const float bv = bvec[(size_t)elem * 32 + row32];
    const float un = u_nom[(size_t)elem * 16 + col16];

    float W[48];

    // ---- N = 2*A*A^T + I: row (lane&31) into W[16..47]; A row j streamed from LDS ----
    #pragma unroll
    for (int j = 0; j < 32; ++j) {
        float acc = 0.f;
        #pragma unroll
        for (int q = 0; q < 4; ++q) {
            float4 v = Av[j * 4 + (q ^ (j & 3))];      // logical block q of A row j
            acc = fmaf(A_row[4*q + 0], v.x, acc);
            acc = fmaf(A_row[4*q + 1], v.y, acc);
            acc = fmaf(A_row[4*q + 2], v.z, acc);
            acc = fmaf(A_row[4*q + 3], v.w, acc);
        }
        float diag = (row32 == j) ? 1.f : 0.f;
        W[16 + j] = fmaf(2.f, acc, diag);
    }
    // A_row regs are now DEAD (all later A uses stream from LDS).

    // ---- in-place Gauss-Jordan: W[16..47] -> Q = N^-1 row (lane&31) ----
    #pragma unroll
    for (int p = 0; p < 32; ++p) {
        float piv = bcastf(W[16 + p], p);
        float d = __builtin_amdgcn_rcpf(piv);
        d = d * (2.f - piv * d);                // one Newton step
        float g = W[16 + p] * d;
        g = (row32 == p) ? (1.f - d) : g;
        float negg = -g;
        #pragma unroll
        for (int j = 0; j < 32; ++j) {
            if (j == p) continue;
            float spj = bcastf(W[16 + j], p);
            W[16 + j] = fmaf(negg, spj, W[16 + j]);
        }
        W[16 + p] = (row32 == p) ? d : negg;
    }

    // ---- QA row (lane&31) into W[0..15]: A rows streamed uniformly ----
    #pragma unroll
    for (int k = 0; k < 16; ++k) W[k] = 0.f;
    #pragma unroll
    for (int m = 0; m < 32; ++m) {
        float qm = W[16 + m];                       // Q[row][m]
        #pragma unroll
        for (int q = 0; q < 4; ++q) {
            float4 v = Av[m * 4 + (q ^ (m & 3))];   // A[m][4q..4q+3]
            W[4*q + 0] = fmaf(qm, v.x, W[4*q + 0]);
            W[4*q + 1] = fmaf(qm, v.y, W[4*q + 1]);
            W[4*q + 2] = fmaf(qm, v.z, W[4*q + 2]);
            W[4*q + 3] = fmaf(qm, v.w, W[4*q + 3]);
        }
    }

    // ---- stage QA rows; lanes<32 overwrite W with [AtQA | AtQ] ----
    if (lane < 32) {
        #pragma unroll
        for (int k = 0; k < 16; ++k) QAT[row32 * 17 + k] = W[k];
    }
    if (lane < 32) {
        #pragma unroll
        for (int m = 0; m < 32; ++m)
            W[16 + m] = QAT[m * 17 + col16];        // AtQ[i][m] = QA[m][i]
        #pragma unroll
        for (int k = 0; k < 16; ++k) W[k] = 0.f;    // AtQA accumulator
        #pragma unroll
        for (int m = 0; m < 32; ++m) {
            float am = W[16 + m];                   // AtQ[i][m]
            #pragma unroll
            for (int q = 0; q < 4; ++q) {
                float4 v = Av[m * 4 + (q ^ (m & 3))];   // A[m][4q..4q+3]
                W[4*q + 0] = fmaf(am, v.x, W[4*q + 0]);
                W[4*q + 1] = fmaf(am, v.y, W[4*q + 1]);
                W[4*q + 2] = fmaf(am, v.z, W[4*q + 2]);
                W[4*q + 3] = fmaf(am, v.w, W[4*q + 3]);
            }
        }
    }

    // ---- fold c = (lanes<32 ? AtQ.b : Q.b); store -c ----
    float cneg;
    {
        float c0 = 0.f, c1 = 0.f;
        #pragma unroll
        for (int m = 0; m < 32; m += 2) {
            c0 = fmaf(W[16 + m], bcastf(bv, m),     c0);
            c1 = fmaf(W[17 + m], bcastf(bv, m + 1), c1);
        }
        cneg = -(c0 + c1);
    }

    // ---- loop constants: znew = sgn*acc + (x + c5*t1 - su) ----
    const float sgn = (lane >= 16 && lane < 32) ? 1.f : -1.f;
    const float c5  = (lane < 32) ? -0.5f : 0.f;
    const float su  = (lane < 32) ? 0.5f * sgn * un : 0.f;

    const int mi = *mi_ptr;
    const int nsteps = (MODE == 0) ? mi : ctl[0];

    const size_t zstride = (size_t)B * 64;
    const size_t zidx = (size_t)elem * 64 + lane;
    const float* zs_end = zstore + (size_t)zcap * zstride;
    float* zs = zstore;

    float z = 0.f;
    unsigned long long m0 = 0ull, m1 = 0ull, b0 = 1ull, b1 = 0ull;

    for (int k = 1; k <= nsteps; ++k) {
        float z16 = swz<SWZ_XOR16>(z);
        float x   = fmaxf(z, 0.f);
        float x16 = fmaxf(z16, 0.f);
        float t1  = x - x16;
        float vs  = (t1 - (z - z16)) + un;          // s, lanes 0-15 valid
        float vh  = fmaf(2.f, x, -z);               // h, lanes 32-63 valid

        float a0 = cneg, a1 = 0.f, a2 = 0.f, a3 = 0.f;
        MACS(a0, a1, a2, a3, vs, vh, W);
        float acc  = (a0 + a1) + (a2 + a3);
        float znew = fmaf(sgn, acc, fmaf(c5, t1, x) - su);

        if (MODE == 0) {
            unsigned long long cy = b0 >> 63;
            b0 <<= 1; b1 = (b1 << 1) | cy;          // b = 1 << k (uniform, SALU)
            unsigned long long any = __ballot(fabsf(znew - z) >= TOL);
            if (any) { m0 |= b0; m1 |= b1; }
            if (zs < zs_end) zs[zidx] = znew;       // checkpoint step k -> slot k-1
            zs += zstride;
        }
        z = znew;
    }

    if (MODE == 0) {
        if (lane == 0) {
            int slot = blockIdx.x & 7;
            atomicOr(flags + 2 * slot,     m0);
            atomicOr(flags + 2 * slot + 1, m1);
        }
    } else {
        float z16b = swz<SWZ_XOR16>(z);
        if (lane < 16) out[(size_t)elem * 16 + lane] = z - z16b;
        out[(size_t)B * 16 + zidx] = z;
    }
}

// S = (first k in [1,mi) with global residual < TOL) + 1, else mi.
__global__ void dys_reduce(const int* __restrict__ mi_ptr,
                           const unsigned long long* __restrict__ flags,
                           int zcap, int* __restrict__ ctl)
{
    if (threadIdx.x != 0) return;
    unsigned long long m0 = 0ull, m1 = 0ull;
    for (int s = 0; s < 8; ++s) { m0 |= flags[2*s]; m1 |= flags[2*s+1]; }
    int mi = *mi_ptr;
    int S = mi;
    for (int k = 1; k < mi && k < 128; ++k) {
        unsigned long long bit = (k < 64) ? ((m0 >> k) & 1ull)
                                          : ((m1 >> (k - 64)) & 1ull);
        if (!bit) { S = k + 1; break; }
    }
    if (S < 1) S = 1;
    ctl[0] = S;
    ctl[1] = (S <= zcap) ? 1 : 0;
}

__global__ __launch_bounds__(256) void dys_gather(
    const int* __restrict__ ctl, const float* __restrict__ zstore,
    float* __restrict__ out, int B)
{
    if (!ctl[1]) return;
    int tid  = blockIdx.x * 256 + threadIdx.x;
    int lane = tid & 63;
    int elem = tid >> 6;
    int S = ctl[0];
    float z = zstore[(size_t)(S - 1) * B * 64 + (size_t)elem * 64 + lane];
    float z16 = swz<SWZ_XOR16>(z);
    if (lane < 16) out[(size_t)elem * 16 + lane] = z - z16;
    out[(size_t)B * 16 + (size_t)elem * 64 + lane] = z;
}

extern "C" void kernel_launch(void* const* d_in, const int* in_sizes, int n_in,
                              void* d_out, int out_size, void* d_ws, size_t ws_size,
                              hipStream_t stream) {
    (void)n_in; (void)out_size;
    const float* u_nom = (const float*)d_in[0];
    const float* Amat  = (const float*)d_in[1];
    const float* bvec  = (const float*)d_in[2];
    const int*   mi    = (const int*)d_in[3];

    const int B = in_sizes[0] / 16;                  // 8192

    unsigned long long* flags = (unsigned long long*)d_ws;
    int* ctl = (int*)((char*)d_ws + WS_CTL_OFF);
    float* zstore = (float*)((char*)d_ws + WS_Z_OFF);

    const size_t stepBytes = (size_t)B * 64 * sizeof(float);   // 2 MB
    int zcap = 0;
    if (ws_size > WS_Z_OFF + stepBytes)
        zcap = (int)((ws_size - WS_Z_OFF) / stepBytes);
    if (zcap > 127) zcap = 127;                      // masks cover k < 128

    hipMemsetAsync(d_ws, 0, 256, stream);            // flags + ctl

    const int blocks = B / WPB;
    dys_pass<0><<<blocks, 64 * WPB, 0, stream>>>(u_nom, Amat, bvec, mi, ctl,
                                                 flags, zstore, zcap, (float*)d_out, B);
    dys_reduce<<<1, 64, 0, stream>>>(mi, flags, zcap, ctl);
    // Fallback replay (early-exits when checkpoints cover S):
    dys_pass<1><<<blocks, 64 * WPB, 0, stream>>>(u_nom, Amat, bvec, mi, ctl,
                                                 flags, zstore, zcap, (float*)d_out, B);
    // Checkpoint gather (early-exits when fallback ran):
    dys_gather<<<B * 64 / 256, 256, 0, stream>>>(ctl, zstore, (float*)d_out, B);
}